// Round 3
// baseline (2150.824 us; speedup 1.0000x reference)
//
#include <hip/hip_runtime.h>
#include <hip/hip_fp16.h>

#define D_DIM 512
#define BM 128
#define BN 256
#define BK 64

#define NC_SHIFT 11      // chunk = col >> 11  (2048 sup rows = 2 MB fp16)
#define NC_SLOT 32       // slots per row in the seg table
#define NPHASE 25        // chunks used: 0..24 (49999>>11 = 24)
#define NW_PAIRS 2000    // wave-pairs; each pair covers 25 rows, two D-halves
#define ROWS_PW 25

typedef _Float16 h8 __attribute__((ext_vector_type(8)));
typedef _Float16 h4 __attribute__((ext_vector_type(4)));
typedef float f32x4 __attribute__((ext_vector_type(4)));

#define LDS_PTR(p) ((__attribute__((address_space(3))) void*)(p))
#define GLB_PTR(p) ((const __attribute__((address_space(1))) void*)(p))

// ---------------- CSR build (chunk-ordered) ----------------

__global__ void k_zero2(int* __restrict__ counts2, int n) {
    int i = blockIdx.x * blockDim.x + threadIdx.x;
    if (i < n) counts2[i] = 0;
}

__global__ void k_count2(const int* __restrict__ row, const int* __restrict__ col,
                         int* __restrict__ counts2, int E) {
    int e = blockIdx.x * blockDim.x + threadIdx.x;
    if (e < E) atomicAdd(&counts2[row[e] * NC_SLOT + (col[e] >> NC_SHIFT)], 1);
}

// per row: total -> counts[row]; in-place exclusive prefix over 32 slots
__global__ void k_rowscan(int* __restrict__ counts2, int* __restrict__ counts, int n) {
    int r = blockIdx.x * blockDim.x + threadIdx.x;
    if (r >= n) return;
    int* p = counts2 + r * NC_SLOT;
    int v[NC_SLOT];
#pragma unroll
    for (int i = 0; i < NC_SLOT / 4; ++i) {
        int4 q = *(const int4*)(p + i * 4);
        v[i * 4] = q.x; v[i * 4 + 1] = q.y; v[i * 4 + 2] = q.z; v[i * 4 + 3] = q.w;
    }
    int run = 0;
#pragma unroll
    for (int i = 0; i < NC_SLOT; ++i) { int t = v[i]; v[i] = run; run += t; }
    counts[r] = run;
#pragma unroll
    for (int i = 0; i < NC_SLOT / 4; ++i) {
        int4 q = {v[i * 4], v[i * 4 + 1], v[i * 4 + 2], v[i * 4 + 3]};
        *(int4*)(p + i * 4) = q;
    }
}

__global__ void k_scan_part(const int* __restrict__ counts, int* __restrict__ offsets,
                            int* __restrict__ bsum, int n) {
    __shared__ int s[1024];
    int t = threadIdx.x;
    int i = blockIdx.x * 1024 + t;
    int v = (i < n) ? counts[i] : 0;
    s[t] = v;
    __syncthreads();
    for (int off = 1; off < 1024; off <<= 1) {
        int x = (t >= off) ? s[t - off] : 0;
        __syncthreads();
        s[t] += x;
        __syncthreads();
    }
    if (i < n) offsets[i] = s[t] - v;
    if (t == 1023) bsum[blockIdx.x] = s[t];
}

__global__ void k_scan_top(int* __restrict__ bsum, int* __restrict__ offsets, int nb, int n) {
    int t = threadIdx.x;
    int v = (t < nb) ? bsum[t] : 0;
    int orig = v;
    for (int off = 1; off < 64; off <<= 1) {
        int u = __shfl_up(v, off, 64);
        if (t >= off) v += u;
    }
    if (t < nb) bsum[t] = v - orig;
    if (t == nb - 1) offsets[n] = v;
}

__global__ void k_scan_add(int* __restrict__ offsets, const int* __restrict__ bsum, int n) {
    int i = blockIdx.x * 1024 + threadIdx.x;
    if (i < n) offsets[i] += bsum[blockIdx.x];
}

// seg[row*32+c] = offsets[row] + rowchunk_prefix ; cursor2 = copy for scatter
__global__ void k_seg(const int* __restrict__ offsets, const int* __restrict__ counts2,
                      int* __restrict__ seg, int* __restrict__ cursor2, int n32) {
    int i = blockIdx.x * blockDim.x + threadIdx.x;
    if (i < n32) {
        int v = offsets[i >> 5] + counts2[i];
        seg[i] = v;
        cursor2[i] = v;
    }
}

__global__ void k_scatter(const int* __restrict__ row, const int* __restrict__ col,
                          const float* __restrict__ ew, int* __restrict__ cursor2,
                          uint2* __restrict__ packed, int E) {
    int e = blockIdx.x * blockDim.x + threadIdx.x;
    if (e < E) {
        int r = row[e], c = col[e];
        int pos = atomicAdd(&cursor2[r * NC_SLOT + (c >> NC_SHIFT)], 1);
        packed[pos] = make_uint2((unsigned)c, __float_as_uint(ew[e]));
    }
}

// ---------------- weight transpose + fp16 convert: wt[n][k] = w[k][n] ----------------

__global__ void k_wt(const float* __restrict__ w, _Float16* __restrict__ wt) {
    __shared__ _Float16 tile[32][33];
    int bx = blockIdx.x & 15, by = blockIdx.x >> 4;
    int tx = threadIdx.x & 31, ty = threadIdx.x >> 5;
    for (int r = 0; r < 32; r += 8)
        tile[ty + r][tx] = (_Float16)w[(size_t)(by * 32 + ty + r) * 512 + bx * 32 + tx];
    __syncthreads();
    for (int r = 0; r < 32; r += 8)
        wt[(size_t)(bx * 32 + ty + r) * 512 + by * 32 + tx] = tile[tx][ty + r];
}

// ---------------- GEMM: sup[m][n] (fp16) = X[m][k] * W[k][n], BN=256 ----------------
// wave w covers 128m x 64n (n-base = w*64)

__launch_bounds__(256)
__global__ void k_gemm(const float* __restrict__ x, const _Float16* __restrict__ wt,
                       _Float16* __restrict__ sup, int M, int nwg) {
    __shared__ __align__(16) unsigned char As[BM * BK * 2];  // 16 KB
    __shared__ __align__(16) unsigned char Bs[BN * BK * 2];  // 32 KB

    // bijective XCD swizzle (m204): orig%8 -> xcd chunk
    const int orig = blockIdx.x;
    const int q = nwg >> 3, r = nwg & 7;
    const int xcd = orig & 7, idx = orig >> 3;
    const int wgid = (xcd < r ? xcd * (q + 1) : r * (q + 1) + (xcd - r) * q) + idx;
    const int m0 = (wgid >> 1) * BM, n0 = (wgid & 1) * BN;

    const int t = threadIdx.x;
    const int lane = t & 63, w = t >> 6;

    f32x4 acc[8][4] = {};

    const int ar_t = t >> 4;
    const int ac_t = (t & 15) * 4;
    const int bn_t = t >> 3;
    const int bk_sw = ((t & 7) * 16) ^ (((t >> 3) & 7) << 4);

    for (int kt = 0; kt < D_DIM / BK; ++kt) {
        const int k0 = kt * BK;
        // B: 8x global_load_lds, 16B each, linear LDS dest, swizzled global src
        for (int j = 0; j < 8; ++j) {
            int n = j * 32 + bn_t;
            const char* src = (const char*)(wt + (size_t)(n0 + n) * 512 + k0) + bk_sw;
            __builtin_amdgcn_global_load_lds(GLB_PTR(src), LDS_PTR(Bs + j * 4096 + t * 16),
                                             16, 0, 0);
        }
        // A: reg-staged fp32->f16, swizzled ds_write
        for (int i = 0; i < 8; ++i) {
            int rr = i * 16 + ar_t;
            int g = m0 + rr;
            if (g >= M) g = M - 1;
            const float4 v = *(const float4*)(x + (size_t)g * 512 + k0 + ac_t);
            h4 hv;
            hv[0] = (_Float16)v.x; hv[1] = (_Float16)v.y;
            hv[2] = (_Float16)v.z; hv[3] = (_Float16)v.w;
            int addr = rr * 128 + ((ac_t * 2) ^ ((rr & 7) << 4));
            *(h4*)(As + addr) = hv;
        }
        __syncthreads();

        for (int ks = 0; ks < 2; ++ks) {
            h8 af[8], bf[4];
            const int kb = ks * 64 + ((lane >> 4) * 16);
#pragma unroll
            for (int mb = 0; mb < 8; ++mb) {
                int rr = mb * 16 + (lane & 15);
                af[mb] = *(const h8*)(As + rr * 128 + (kb ^ ((rr & 7) << 4)));
            }
#pragma unroll
            for (int nb = 0; nb < 4; ++nb) {
                int n = w * 64 + nb * 16 + (lane & 15);
                bf[nb] = *(const h8*)(Bs + n * 128 + (kb ^ ((n & 7) << 4)));
            }
#pragma unroll
            for (int mb = 0; mb < 8; ++mb)
#pragma unroll
                for (int nb = 0; nb < 4; ++nb)
                    acc[mb][nb] = __builtin_amdgcn_mfma_f32_16x16x32_f16(
                        af[mb], bf[nb], acc[mb][nb], 0, 0, 0);
        }
        __syncthreads();
    }

    const int cr = (lane >> 4) * 4, cc = lane & 15;
#pragma unroll
    for (int mb = 0; mb < 8; ++mb) {
#pragma unroll
        for (int nb = 0; nb < 4; ++nb) {
            int gn = n0 + w * 64 + nb * 16 + cc;
#pragma unroll
            for (int qq = 0; qq < 4; ++qq) {
                int gm = m0 + mb * 16 + cr + qq;
                if (gm < M)
                    sup[(size_t)gm * 512 + gn] = (_Float16)acc[mb][nb][qq];
            }
        }
    }
}

// ---------------- SpMM: persistent, chunk-phase-aligned ----------------
// 1000 blocks x 4 waves = 4000 waves; wave-pair owns 25 rows (stride 2000),
// each wave handles 256 of the 512 output cols. Sweeps 25 col-chunks in
// lock-step so concurrent gathers hit a ~2-4 MB L2-resident window.

__launch_bounds__(256)
__global__ void k_spmm(const _Float16* __restrict__ sup, const uint2* __restrict__ packed,
                       const int* __restrict__ seg, const float* __restrict__ bias,
                       float* __restrict__ out) {
    const int w = blockIdx.x * 4 + (threadIdx.x >> 6);
    const int pair = w >> 1, half = w & 1, l = threadIdx.x & 63;
    const int dcol = half * 256 + l * 4;
    const _Float16* __restrict__ supl = sup + dcol;

    const float4 b4 = *(const float4*)(bias + dcol);
    f32x4 bias4 = {b4.x, b4.y, b4.z, b4.w};

    f32x4 acc[ROWS_PW];
    int s_[ROWS_PW];
#pragma unroll
    for (int rr = 0; rr < ROWS_PW; ++rr) {
        acc[rr] = bias4;
        s_[rr] = seg[(pair + rr * NW_PAIRS) * NC_SLOT];
    }

    for (int c = 0; c < NPHASE; ++c) {
#pragma unroll
        for (int rr = 0; rr < ROWS_PW; ++rr) {
            const int e = seg[(pair + rr * NW_PAIRS) * NC_SLOT + c + 1];  // end of chunk c
            int s = s_[rr];
            for (; s < e; ++s) {
                uint2 p = packed[s];
                float wgt = __uint_as_float(p.y);
                h4 h = *(const h4*)(supl + (size_t)p.x * 512);
                acc[rr][0] += wgt * (float)h[0];
                acc[rr][1] += wgt * (float)h[1];
                acc[rr][2] += wgt * (float)h[2];
                acc[rr][3] += wgt * (float)h[3];
            }
            s_[rr] = e;
        }
    }

#pragma unroll
    for (int rr = 0; rr < ROWS_PW; ++rr) {
        float4 o = {acc[rr][0], acc[rr][1], acc[rr][2], acc[rr][3]};
        *(float4*)(out + (size_t)(pair + rr * NW_PAIRS) * 512 + dcol) = o;
    }
}

// ---------------- launch ----------------

extern "C" void kernel_launch(void* const* d_in, const int* in_sizes, int n_in,
                              void* d_out, int out_size, void* d_ws, size_t ws_size,
                              hipStream_t stream) {
    const float* x      = (const float*)d_in[0];
    const float* weight = (const float*)d_in[1];
    const float* bias   = (const float*)d_in[2];
    const int*   row    = (const int*)d_in[3];
    const int*   col    = (const int*)d_in[4];
    const float* ew     = (const float*)d_in[5];
    const int M = in_sizes[0] / D_DIM;   // 50000
    const int E = in_sizes[3];           // 1600000
    float* out = (float*)d_out;

    char* ws = (char*)d_ws;
    size_t off = 0;
    auto alloc = [&](size_t bytes) {
        void* p = ws + off;
        off = (off + bytes + 255) & ~(size_t)255;
        return p;
    };
    _Float16* sup  = (_Float16*)alloc((size_t)M * D_DIM * 2);        // 51.2 MB
    _Float16* wt   = (_Float16*)alloc((size_t)512 * 512 * 2);        // 0.5 MB
    int* counts    = (int*)alloc((size_t)M * 4);                     // 0.2 MB
    int* offsets   = (int*)alloc((size_t)(M + 1) * 4);               // 0.2 MB
    int* counts2   = (int*)alloc((size_t)M * NC_SLOT * 4);           // 6.4 MB
    int* seg       = (int*)alloc((size_t)M * NC_SLOT * 4);           // 6.4 MB
    int* cursor2   = (int*)alloc((size_t)M * NC_SLOT * 4);           // 6.4 MB
    int* bsum      = (int*)alloc(64 * 4);
    uint2* packed  = (uint2*)alloc((size_t)E * 8);                   // 12.8 MB
    (void)ws_size; (void)n_in; (void)out_size;

    const int n32 = M * NC_SLOT;

    // CSR build, chunk-ordered
    k_zero2<<<(n32 + 255) / 256, 256, 0, stream>>>(counts2, n32);
    k_count2<<<(E + 255) / 256, 256, 0, stream>>>(row, col, counts2, E);
    k_rowscan<<<(M + 255) / 256, 256, 0, stream>>>(counts2, counts, M);
    const int SB = (M + 1023) / 1024;  // 49
    k_scan_part<<<SB, 1024, 0, stream>>>(counts, offsets, bsum, M);
    k_scan_top<<<1, 64, 0, stream>>>(bsum, offsets, SB, M);
    k_scan_add<<<SB, 1024, 0, stream>>>(offsets, bsum, M);
    k_seg<<<(n32 + 255) / 256, 256, 0, stream>>>(offsets, counts2, seg, cursor2, n32);
    k_scatter<<<(E + 255) / 256, 256, 0, stream>>>(row, col, ew, cursor2, packed, E);

    // dense path
    k_wt<<<256, 256, 0, stream>>>(weight, wt);
    const int nwg = ((M + BM - 1) / BM) * (D_DIM / BN);  // 391*2 = 782
    k_gemm<<<nwg, 256, 0, stream>>>(x, wt, sup, M, nwg);

    // gather-accumulate, persistent phase-aligned
    k_spmm<<<NW_PAIRS / 2, 256, 0, stream>>>(sup, packed, seg, bias, out);
}

// Round 5
// 655.577 us; speedup vs baseline: 3.2808x; 3.2808x over previous
//
#include <hip/hip_runtime.h>
#include <hip/hip_fp16.h>

#define D_DIM 512
#define BM 128
#define BN 256
#define BK 64

typedef _Float16 h8 __attribute__((ext_vector_type(8)));
typedef _Float16 h4 __attribute__((ext_vector_type(4)));
typedef float f32x4 __attribute__((ext_vector_type(4)));
typedef unsigned int u32x4 __attribute__((ext_vector_type(4)));

#define LDS_PTR(p) ((__attribute__((address_space(3))) void*)(p))
#define GLB_PTR(p) ((const __attribute__((address_space(1))) void*)(p))

// ---------------- CSR build ----------------

__global__ void k_count(const int* __restrict__ row, int* __restrict__ counts, int E) {
    int e = blockIdx.x * blockDim.x + threadIdx.x;
    if (e < E) atomicAdd(&counts[row[e]], 1);
}

__global__ void k_scan_part(const int* __restrict__ counts, int* __restrict__ offsets,
                            int* __restrict__ bsum, int n) {
    __shared__ int s[1024];
    int t = threadIdx.x;
    int i = blockIdx.x * 1024 + t;
    int v = (i < n) ? counts[i] : 0;
    s[t] = v;
    __syncthreads();
    for (int off = 1; off < 1024; off <<= 1) {
        int x = (t >= off) ? s[t - off] : 0;
        __syncthreads();
        s[t] += x;
        __syncthreads();
    }
    if (i < n) offsets[i] = s[t] - v;          // block-local exclusive
    if (t == 1023) bsum[blockIdx.x] = s[t];    // block total
}

__global__ void k_scan_top(int* __restrict__ bsum, int* __restrict__ offsets, int nb, int n) {
    int t = threadIdx.x;  // 64 threads
    int v = (t < nb) ? bsum[t] : 0;
    int orig = v;
    for (int off = 1; off < 64; off <<= 1) {
        int u = __shfl_up(v, off, 64);
        if (t >= off) v += u;
    }
    if (t < nb) bsum[t] = v - orig;            // exclusive block offsets
    if (t == nb - 1) offsets[n] = v;           // grand total = E
}

__global__ void k_scan_add(int* __restrict__ offsets, int* __restrict__ cursor,
                           const int* __restrict__ bsum, int n) {
    int i = blockIdx.x * 1024 + threadIdx.x;
    if (i < n) {
        int o = offsets[i] + bsum[blockIdx.x];
        offsets[i] = o;
        cursor[i] = o;
    }
}

__global__ void k_scatter(const int* __restrict__ row, const int* __restrict__ col,
                          const float* __restrict__ ew, int* __restrict__ cursor,
                          uint2* __restrict__ packed, int E) {
    int e = blockIdx.x * blockDim.x + threadIdx.x;
    if (e < E) {
        int r = row[e];
        int pos = atomicAdd(&cursor[r], 1);
        packed[pos] = make_uint2((unsigned)col[e], __float_as_uint(ew[e]));
    }
}

// ---------------- weight transpose + fp16 convert: wt[n][k] = w[k][n] ----------------

__global__ void k_wt(const float* __restrict__ w, _Float16* __restrict__ wt) {
    __shared__ _Float16 tile[32][33];
    int bx = blockIdx.x & 15, by = blockIdx.x >> 4;
    int tx = threadIdx.x & 31, ty = threadIdx.x >> 5;
    for (int r = 0; r < 32; r += 8)
        tile[ty + r][tx] = (_Float16)w[(size_t)(by * 32 + ty + r) * 512 + bx * 32 + tx];
    __syncthreads();
    for (int r = 0; r < 32; r += 8)
        wt[(size_t)(bx * 32 + ty + r) * 512 + by * 32 + tx] = tile[tx][ty + r];
}

// ---------------- GEMM: sup[m][n] (fp16) = X[m][k] * W[k][n], BN=256 ----------------
// wave w covers 128m x 64n (n-base = w*64). Verified in R3 run.

__launch_bounds__(256)
__global__ void k_gemm(const float* __restrict__ x, const _Float16* __restrict__ wt,
                       _Float16* __restrict__ sup, int M, int nwg) {
    __shared__ __align__(16) unsigned char As[BM * BK * 2];  // 16 KB
    __shared__ __align__(16) unsigned char Bs[BN * BK * 2];  // 32 KB

    // bijective XCD swizzle (m204)
    const int orig = blockIdx.x;
    const int q = nwg >> 3, r = nwg & 7;
    const int xcd = orig & 7, idx = orig >> 3;
    const int wgid = (xcd < r ? xcd * (q + 1) : r * (q + 1) + (xcd - r) * q) + idx;
    const int m0 = (wgid >> 1) * BM, n0 = (wgid & 1) * BN;

    const int t = threadIdx.x;
    const int lane = t & 63, w = t >> 6;

    f32x4 acc[8][4] = {};

    const int ar_t = t >> 4;
    const int ac_t = (t & 15) * 4;
    const int bn_t = t >> 3;
    const int bk_sw = ((t & 7) * 16) ^ (((t >> 3) & 7) << 4);

    for (int kt = 0; kt < D_DIM / BK; ++kt) {
        const int k0 = kt * BK;
        // B: 8x global_load_lds, 16B each, linear LDS dest, swizzled global src
        for (int j = 0; j < 8; ++j) {
            int n = j * 32 + bn_t;
            const char* src = (const char*)(wt + (size_t)(n0 + n) * 512 + k0) + bk_sw;
            __builtin_amdgcn_global_load_lds(GLB_PTR(src), LDS_PTR(Bs + j * 4096 + t * 16),
                                             16, 0, 0);
        }
        // A: reg-staged fp32->f16, swizzled ds_write
        for (int i = 0; i < 8; ++i) {
            int rr = i * 16 + ar_t;
            int g = m0 + rr;
            if (g >= M) g = M - 1;
            const float4 v = *(const float4*)(x + (size_t)g * 512 + k0 + ac_t);
            h4 hv;
            hv[0] = (_Float16)v.x; hv[1] = (_Float16)v.y;
            hv[2] = (_Float16)v.z; hv[3] = (_Float16)v.w;
            int addr = rr * 128 + ((ac_t * 2) ^ ((rr & 7) << 4));
            *(h4*)(As + addr) = hv;
        }
        __syncthreads();

        for (int ks = 0; ks < 2; ++ks) {
            h8 af[8], bf[4];
            const int kb = ks * 64 + ((lane >> 4) * 16);
#pragma unroll
            for (int mb = 0; mb < 8; ++mb) {
                int rr = mb * 16 + (lane & 15);
                af[mb] = *(const h8*)(As + rr * 128 + (kb ^ ((rr & 7) << 4)));
            }
#pragma unroll
            for (int nb = 0; nb < 4; ++nb) {
                int n = w * 64 + nb * 16 + (lane & 15);
                bf[nb] = *(const h8*)(Bs + n * 128 + (kb ^ ((n & 7) << 4)));
            }
#pragma unroll
            for (int mb = 0; mb < 8; ++mb)
#pragma unroll
                for (int nb = 0; nb < 4; ++nb)
                    acc[mb][nb] = __builtin_amdgcn_mfma_f32_16x16x32_f16(
                        af[mb], bf[nb], acc[mb][nb], 0, 0, 0);
        }
        __syncthreads();
    }

    const int cr = (lane >> 4) * 4, cc = lane & 15;
#pragma unroll
    for (int mb = 0; mb < 8; ++mb) {
#pragma unroll
        for (int nb = 0; nb < 4; ++nb) {
            int gn = n0 + w * 64 + nb * 16 + cc;
#pragma unroll
            for (int qq = 0; qq < 4; ++qq) {
                int gm = m0 + mb * 16 + cr + qq;
                if (gm < M)
                    sup[(size_t)gm * 512 + gn] = (_Float16)acc[mb][nb][qq];
            }
        }
    }
}

// ---------------- SpMM: R1 structure (4 rows/block, ILP-8) + nt hints ----------------

__global__ void k_spmm(const _Float16* __restrict__ sup, const uint2* __restrict__ packed,
                       const int* __restrict__ offsets, const float* __restrict__ bias,
                       float* __restrict__ out, int M) {
    const int i = blockIdx.x * 4 + (threadIdx.x >> 6);
    if (i >= M) return;
    const int l = threadIdx.x & 63;
    const int s0 = offsets[i], s1 = offsets[i + 1];
    const _Float16* __restrict__ supl = sup + l * 8;

    float acc[8];
    {
        const float4 b0 = *(const float4*)(bias + l * 8);
        const float4 b1 = *(const float4*)(bias + l * 8 + 4);
        acc[0] = b0.x; acc[1] = b0.y; acc[2] = b0.z; acc[3] = b0.w;
        acc[4] = b1.x; acc[5] = b1.y; acc[6] = b1.z; acc[7] = b1.w;
    }

    int e = s0;
    if ((e & 1) && e < s1) {
        uint2 p = packed[e];
        float wgt = __uint_as_float(p.y);
        h8 h = *(const h8*)(supl + (size_t)p.x * 512);
#pragma unroll
        for (int j = 0; j < 8; ++j) acc[j] += wgt * (float)h[j];
        ++e;
    }
    for (; e + 8 <= s1; e += 8) {
        const u32x4 q0 = __builtin_nontemporal_load((const u32x4*)(packed + e));
        const u32x4 q1 = __builtin_nontemporal_load((const u32x4*)(packed + e + 2));
        const u32x4 q2 = __builtin_nontemporal_load((const u32x4*)(packed + e + 4));
        const u32x4 q3 = __builtin_nontemporal_load((const u32x4*)(packed + e + 6));
        const h8 h0 = *(const h8*)(supl + (size_t)q0[0] * 512);
        const h8 h1 = *(const h8*)(supl + (size_t)q0[2] * 512);
        const h8 h2 = *(const h8*)(supl + (size_t)q1[0] * 512);
        const h8 h3 = *(const h8*)(supl + (size_t)q1[2] * 512);
        const h8 h4v = *(const h8*)(supl + (size_t)q2[0] * 512);
        const h8 h5 = *(const h8*)(supl + (size_t)q2[2] * 512);
        const h8 h6 = *(const h8*)(supl + (size_t)q3[0] * 512);
        const h8 h7 = *(const h8*)(supl + (size_t)q3[2] * 512);
        const float w0 = __uint_as_float(q0[1]), w1 = __uint_as_float(q0[3]);
        const float w2 = __uint_as_float(q1[1]), w3 = __uint_as_float(q1[3]);
        const float w4 = __uint_as_float(q2[1]), w5 = __uint_as_float(q2[3]);
        const float w6 = __uint_as_float(q3[1]), w7 = __uint_as_float(q3[3]);
#pragma unroll
        for (int j = 0; j < 8; ++j) {
            float a = acc[j];
            a += w0 * (float)h0[j];
            a += w1 * (float)h1[j];
            a += w2 * (float)h2[j];
            a += w3 * (float)h3[j];
            a += w4 * (float)h4v[j];
            a += w5 * (float)h5[j];
            a += w6 * (float)h6[j];
            a += w7 * (float)h7[j];
            acc[j] = a;
        }
    }
    for (; e < s1; ++e) {
        uint2 p = packed[e];
        float wgt = __uint_as_float(p.y);
        h8 h = *(const h8*)(supl + (size_t)p.x * 512);
#pragma unroll
        for (int j = 0; j < 8; ++j) acc[j] += wgt * (float)h[j];
    }

    f32x4 o0 = {acc[0], acc[1], acc[2], acc[3]};
    f32x4 o1 = {acc[4], acc[5], acc[6], acc[7]};
    __builtin_nontemporal_store(o0, (f32x4*)(out + (size_t)i * 512 + l * 8));
    __builtin_nontemporal_store(o1, (f32x4*)(out + (size_t)i * 512 + l * 8 + 4));
}

// ---------------- launch ----------------

extern "C" void kernel_launch(void* const* d_in, const int* in_sizes, int n_in,
                              void* d_out, int out_size, void* d_ws, size_t ws_size,
                              hipStream_t stream) {
    const float* x      = (const float*)d_in[0];
    const float* weight = (const float*)d_in[1];
    const float* bias   = (const float*)d_in[2];
    const int*   row    = (const int*)d_in[3];
    const int*   col    = (const int*)d_in[4];
    const float* ew     = (const float*)d_in[5];
    const int M = in_sizes[0] / D_DIM;   // 50000
    const int E = in_sizes[3];           // 1600000
    float* out = (float*)d_out;

    char* ws = (char*)d_ws;
    size_t off = 0;
    auto alloc = [&](size_t bytes) {
        void* p = ws + off;
        off = (off + bytes + 255) & ~(size_t)255;
        return p;
    };
    _Float16* sup  = (_Float16*)alloc((size_t)M * D_DIM * 2);   // 51.2 MB
    _Float16* wt   = (_Float16*)alloc((size_t)512 * 512 * 2);
    int* counts    = (int*)alloc((size_t)M * 4);
    int* offsets   = (int*)alloc((size_t)(M + 1) * 4);
    int* cursor    = (int*)alloc((size_t)M * 4);
    int* bsum      = (int*)alloc(64 * 4);
    uint2* packed  = (uint2*)alloc((size_t)E * 8);              // 12.8 MB
    (void)ws_size; (void)n_in; (void)out_size;

    // CSR build
    (void)hipMemsetAsync(counts, 0, (size_t)M * 4, stream);
    k_count<<<(E + 255) / 256, 256, 0, stream>>>(row, counts, E);
    const int SB = (M + 1023) / 1024;  // 49
    k_scan_part<<<SB, 1024, 0, stream>>>(counts, offsets, bsum, M);
    k_scan_top<<<1, 64, 0, stream>>>(bsum, offsets, SB, M);
    k_scan_add<<<SB, 1024, 0, stream>>>(offsets, cursor, bsum, M);
    k_scatter<<<(E + 255) / 256, 256, 0, stream>>>(row, col, ew, cursor, packed, E);

    // dense path
    k_wt<<<256, 256, 0, stream>>>(weight, wt);
    const int nwg = ((M + BM - 1) / BM) * (D_DIM / BN);  // 391*2 = 782
    k_gemm<<<nwg, 256, 0, stream>>>(x, wt, sup, M, nwg);

    // gather-accumulate
    k_spmm<<<(M + 3) / 4, 256, 0, stream>>>(sup, packed, offsets, bias, out, M);
}

// Round 6
// 638.517 us; speedup vs baseline: 3.3685x; 1.0267x over previous
//
#include <hip/hip_runtime.h>
#include <hip/hip_fp16.h>

#define D_DIM 512
#define BM 128
#define BN 256
#define BK 64

typedef _Float16 h8 __attribute__((ext_vector_type(8)));
typedef _Float16 h4 __attribute__((ext_vector_type(4)));
typedef _Float16 h2 __attribute__((ext_vector_type(2)));
typedef float f32x4 __attribute__((ext_vector_type(4)));
typedef unsigned int u32x4 __attribute__((ext_vector_type(4)));

#define LDS_PTR(p) ((__attribute__((address_space(3))) void*)(p))
#define GLB_PTR(p) ((const __attribute__((address_space(1))) void*)(p))

// ---------------- CSR build ----------------

__global__ void k_count(const int* __restrict__ row, int* __restrict__ counts, int E) {
    int e = blockIdx.x * blockDim.x + threadIdx.x;
    if (e < E) atomicAdd(&counts[row[e]], 1);
}

__global__ void k_scan_part(const int* __restrict__ counts, int* __restrict__ offsets,
                            int* __restrict__ bsum, int n) {
    __shared__ int s[1024];
    int t = threadIdx.x;
    int i = blockIdx.x * 1024 + t;
    int v = (i < n) ? counts[i] : 0;
    s[t] = v;
    __syncthreads();
    for (int off = 1; off < 1024; off <<= 1) {
        int x = (t >= off) ? s[t - off] : 0;
        __syncthreads();
        s[t] += x;
        __syncthreads();
    }
    if (i < n) offsets[i] = s[t] - v;          // block-local exclusive
    if (t == 1023) bsum[blockIdx.x] = s[t];    // block total
}

__global__ void k_scan_top(int* __restrict__ bsum, int* __restrict__ offsets, int nb, int n) {
    int t = threadIdx.x;  // 64 threads
    int v = (t < nb) ? bsum[t] : 0;
    int orig = v;
    for (int off = 1; off < 64; off <<= 1) {
        int u = __shfl_up(v, off, 64);
        if (t >= off) v += u;
    }
    if (t < nb) bsum[t] = v - orig;            // exclusive block offsets
    if (t == nb - 1) offsets[n] = v;           // grand total = E
}

__global__ void k_scan_add(int* __restrict__ offsets, int* __restrict__ cursor,
                           const int* __restrict__ bsum, int n) {
    int i = blockIdx.x * 1024 + threadIdx.x;
    if (i < n) {
        int o = offsets[i] + bsum[blockIdx.x];
        offsets[i] = o;
        cursor[i] = o;
    }
}

__global__ void k_scatter(const int* __restrict__ row, const int* __restrict__ col,
                          const float* __restrict__ ew, int* __restrict__ cursor,
                          uint2* __restrict__ packed, int E) {
    int e = blockIdx.x * blockDim.x + threadIdx.x;
    if (e < E) {
        int r = row[e];
        int pos = atomicAdd(&cursor[r], 1);
        packed[pos] = make_uint2((unsigned)col[e], __float_as_uint(ew[e]));
    }
}

// ---------------- weight transpose + fp16 convert: wt[n][k] = w[k][n] ----------------

__global__ void k_wt(const float* __restrict__ w, _Float16* __restrict__ wt) {
    __shared__ _Float16 tile[32][33];
    int bx = blockIdx.x & 15, by = blockIdx.x >> 4;
    int tx = threadIdx.x & 31, ty = threadIdx.x >> 5;
    for (int r = 0; r < 32; r += 8)
        tile[ty + r][tx] = (_Float16)w[(size_t)(by * 32 + ty + r) * 512 + bx * 32 + tx];
    __syncthreads();
    for (int r = 0; r < 32; r += 8)
        wt[(size_t)(bx * 32 + ty + r) * 512 + by * 32 + tx] = tile[tx][ty + r];
}

// ---------------- GEMM: sup[m][n] (fp16) = X[m][k] * W[k][n], BN=256 ----------------

__launch_bounds__(256)
__global__ void k_gemm(const float* __restrict__ x, const _Float16* __restrict__ wt,
                       _Float16* __restrict__ sup, int M, int nwg) {
    __shared__ __align__(16) unsigned char As[BM * BK * 2];  // 16 KB
    __shared__ __align__(16) unsigned char Bs[BN * BK * 2];  // 32 KB

    // bijective XCD swizzle (m204)
    const int orig = blockIdx.x;
    const int q = nwg >> 3, r = nwg & 7;
    const int xcd = orig & 7, idx = orig >> 3;
    const int wgid = (xcd < r ? xcd * (q + 1) : r * (q + 1) + (xcd - r) * q) + idx;
    const int m0 = (wgid >> 1) * BM, n0 = (wgid & 1) * BN;

    const int t = threadIdx.x;
    const int lane = t & 63, w = t >> 6;

    f32x4 acc[8][4] = {};

    const int ar_t = t >> 4;
    const int ac_t = (t & 15) * 4;
    const int bn_t = t >> 3;
    const int bk_sw = ((t & 7) * 16) ^ (((t >> 3) & 7) << 4);

    for (int kt = 0; kt < D_DIM / BK; ++kt) {
        const int k0 = kt * BK;
        // B: 8x global_load_lds, 16B each, linear LDS dest, swizzled global src
        for (int j = 0; j < 8; ++j) {
            int n = j * 32 + bn_t;
            const char* src = (const char*)(wt + (size_t)(n0 + n) * 512 + k0) + bk_sw;
            __builtin_amdgcn_global_load_lds(GLB_PTR(src), LDS_PTR(Bs + j * 4096 + t * 16),
                                             16, 0, 0);
        }
        // A: reg-staged fp32->f16, swizzled ds_write
        for (int i = 0; i < 8; ++i) {
            int rr = i * 16 + ar_t;
            int g = m0 + rr;
            if (g >= M) g = M - 1;
            const float4 v = *(const float4*)(x + (size_t)g * 512 + k0 + ac_t);
            h4 hv;
            hv[0] = (_Float16)v.x; hv[1] = (_Float16)v.y;
            hv[2] = (_Float16)v.z; hv[3] = (_Float16)v.w;
            int addr = rr * 128 + ((ac_t * 2) ^ ((rr & 7) << 4));
            *(h4*)(As + addr) = hv;
        }
        __syncthreads();

        for (int ks = 0; ks < 2; ++ks) {
            h8 af[8], bf[4];
            const int kb = ks * 64 + ((lane >> 4) * 16);
#pragma unroll
            for (int mb = 0; mb < 8; ++mb) {
                int rr = mb * 16 + (lane & 15);
                af[mb] = *(const h8*)(As + rr * 128 + (kb ^ ((rr & 7) << 4)));
            }
#pragma unroll
            for (int nb = 0; nb < 4; ++nb) {
                int n = w * 64 + nb * 16 + (lane & 15);
                bf[nb] = *(const h8*)(Bs + n * 128 + (kb ^ ((n & 7) << 4)));
            }
#pragma unroll
            for (int mb = 0; mb < 8; ++mb)
#pragma unroll
                for (int nb = 0; nb < 4; ++nb)
                    acc[mb][nb] = __builtin_amdgcn_mfma_f32_16x16x32_f16(
                        af[mb], bf[nb], acc[mb][nb], 0, 0, 0);
        }
        __syncthreads();
    }

    const int cr = (lane >> 4) * 4, cc = lane & 15;
#pragma unroll
    for (int mb = 0; mb < 8; ++mb) {
#pragma unroll
        for (int nb = 0; nb < 4; ++nb) {
            int gn = n0 + w * 64 + nb * 16 + cc;
#pragma unroll
            for (int qq = 0; qq < 4; ++qq) {
                int gm = m0 + mb * 16 + cr + qq;
                if (gm < M)
                    sup[(size_t)gm * 512 + gn] = (_Float16)acc[mb][nb][qq];
            }
        }
    }
}

// ---------------- SpMM: D-quartered gather, quarter pinned to XCD pair ----------------
// block b: quarter qd = b&3 (XCD = b%8 -> quarter q only on XCDs {q, q+4}),
// rows (b>>2)*4 + wave. Each wave: 1 row x 128 cols, lane owns 2 cols.
// Gather = 256B/edge -> 4x larger L2 reuse window (rows) than full-D.

__global__ void k_spmm(const _Float16* __restrict__ sup, const uint2* __restrict__ packed,
                       const int* __restrict__ offsets, const float* __restrict__ bias,
                       float* __restrict__ out, int M) {
    const int b = blockIdx.x;
    const int qd = b & 3;
    const int i = (b >> 2) * 4 + (threadIdx.x >> 6);
    if (i >= M) return;
    const int l = threadIdx.x & 63;
    const int dcol = qd * 128 + l * 2;
    const _Float16* __restrict__ supl = sup + dcol;
    const int s0 = offsets[i], s1 = offsets[i + 1];

    const float2 bb = *(const float2*)(bias + dcol);
    float a0 = bb.x, a1 = bb.y;

    int e = s0;
    if ((e & 1) && e < s1) {
        uint2 p = packed[e];
        float wgt = __uint_as_float(p.y);
        h2 h = *(const h2*)(supl + (size_t)p.x * 512);
        a0 += wgt * (float)h[0];
        a1 += wgt * (float)h[1];
        ++e;
    }
    for (; e + 8 <= s1; e += 8) {
        const u32x4 q0 = *(const u32x4*)(packed + e);
        const u32x4 q1 = *(const u32x4*)(packed + e + 2);
        const u32x4 q2 = *(const u32x4*)(packed + e + 4);
        const u32x4 q3 = *(const u32x4*)(packed + e + 6);
        const h2 h0 = *(const h2*)(supl + (size_t)q0[0] * 512);
        const h2 h1 = *(const h2*)(supl + (size_t)q0[2] * 512);
        const h2 h2v = *(const h2*)(supl + (size_t)q1[0] * 512);
        const h2 h3 = *(const h2*)(supl + (size_t)q1[2] * 512);
        const h2 h4v = *(const h2*)(supl + (size_t)q2[0] * 512);
        const h2 h5 = *(const h2*)(supl + (size_t)q2[2] * 512);
        const h2 h6 = *(const h2*)(supl + (size_t)q3[0] * 512);
        const h2 h7 = *(const h2*)(supl + (size_t)q3[2] * 512);
        const float w0 = __uint_as_float(q0[1]), w1 = __uint_as_float(q0[3]);
        const float w2 = __uint_as_float(q1[1]), w3 = __uint_as_float(q1[3]);
        const float w4 = __uint_as_float(q2[1]), w5 = __uint_as_float(q2[3]);
        const float w6 = __uint_as_float(q3[1]), w7 = __uint_as_float(q3[3]);
        a0 += w0 * (float)h0[0] + w1 * (float)h1[0] + w2 * (float)h2v[0] + w3 * (float)h3[0]
            + w4 * (float)h4v[0] + w5 * (float)h5[0] + w6 * (float)h6[0] + w7 * (float)h7[0];
        a1 += w0 * (float)h0[1] + w1 * (float)h1[1] + w2 * (float)h2v[1] + w3 * (float)h3[1]
            + w4 * (float)h4v[1] + w5 * (float)h5[1] + w6 * (float)h6[1] + w7 * (float)h7[1];
    }
    for (; e < s1; ++e) {
        uint2 p = packed[e];
        float wgt = __uint_as_float(p.y);
        h2 h = *(const h2*)(supl + (size_t)p.x * 512);
        a0 += wgt * (float)h[0];
        a1 += wgt * (float)h[1];
    }

    *(float2*)(out + (size_t)i * 512 + dcol) = make_float2(a0, a1);
}

// ---------------- launch ----------------

extern "C" void kernel_launch(void* const* d_in, const int* in_sizes, int n_in,
                              void* d_out, int out_size, void* d_ws, size_t ws_size,
                              hipStream_t stream) {
    const float* x      = (const float*)d_in[0];
    const float* weight = (const float*)d_in[1];
    const float* bias   = (const float*)d_in[2];
    const int*   row    = (const int*)d_in[3];
    const int*   col    = (const int*)d_in[4];
    const float* ew     = (const float*)d_in[5];
    const int M = in_sizes[0] / D_DIM;   // 50000
    const int E = in_sizes[3];           // 1600000
    float* out = (float*)d_out;

    char* ws = (char*)d_ws;
    size_t off = 0;
    auto alloc = [&](size_t bytes) {
        void* p = ws + off;
        off = (off + bytes + 255) & ~(size_t)255;
        return p;
    };
    _Float16* sup  = (_Float16*)alloc((size_t)M * D_DIM * 2);   // 51.2 MB
    _Float16* wt   = (_Float16*)alloc((size_t)512 * 512 * 2);
    int* counts    = (int*)alloc((size_t)M * 4);
    int* offsets   = (int*)alloc((size_t)(M + 1) * 4);
    int* cursor    = (int*)alloc((size_t)M * 4);
    int* bsum      = (int*)alloc(64 * 4);
    uint2* packed  = (uint2*)alloc((size_t)E * 8);              // 12.8 MB
    (void)ws_size; (void)n_in; (void)out_size;

    // CSR build
    (void)hipMemsetAsync(counts, 0, (size_t)M * 4, stream);
    k_count<<<(E + 255) / 256, 256, 0, stream>>>(row, counts, E);
    const int SB = (M + 1023) / 1024;  // 49
    k_scan_part<<<SB, 1024, 0, stream>>>(counts, offsets, bsum, M);
    k_scan_top<<<1, 64, 0, stream>>>(bsum, offsets, SB, M);
    k_scan_add<<<SB, 1024, 0, stream>>>(offsets, cursor, bsum, M);
    k_scatter<<<(E + 255) / 256, 256, 0, stream>>>(row, col, ew, cursor, packed, E);

    // dense path
    k_wt<<<256, 256, 0, stream>>>(weight, wt);
    const int nwg = ((M + BM - 1) / BM) * (D_DIM / BN);  // 391*2 = 782
    k_gemm<<<nwg, 256, 0, stream>>>(x, wt, sup, M, nwg);

    // gather-accumulate: 4 quarter-blocks per 4-row group
    const int rowgroups = (M + 3) / 4;
    k_spmm<<<rowgroups * 4, 256, 0, stream>>>(sup, packed, offsets, bias, out, M);
}